// Round 1
// baseline (816.928 us; speedup 1.0000x reference)
//
#include <hip/hip_runtime.h>
#include <stdint.h>

#define HID   128
#define OUT   4096
#define NWG   16
#define SLICE 256          // OUT / NWG
#define NT    256
#define LD    132          // padded leading dim (16B aligned, breaks bank aliasing)

// ---------------- Kernel 1: xW1 = clip(x,0,1) @ W1  (one-time, bandwidth-bound) ----
__global__ __launch_bounds__(NT) void k_xw1(const float* __restrict__ x,
                                            const float* __restrict__ W1,
                                            float* __restrict__ xW1) {
  __shared__ float red[NT];
  const int t = threadIdx.x;
  const int c = t & (HID - 1);
  const int half = t >> 7;
  const int row0 = blockIdx.x * 256 + half * 128;
  float acc = 0.f;
#pragma unroll 4
  for (int rr = 0; rr < 128; ++rr) {
    const int r = row0 + rr;
    float rx = x[r];
    rx = fminf(fmaxf(rx, 0.f), 1.f);
    acc = fmaf(rx, W1[(size_t)r * HID + c], acc);
  }
  red[t] = acc;
  __syncthreads();
  if (t < HID) atomicAdd(&xW1[c], red[t] + red[t + HID]);
}

// ---------------- Kernel 2: persistent EP iteration kernel --------------------------
// 16 WGs, each owns 256 columns of W2 (in LDS) and the matching o-slice.
// h (128) + its Adam state replicated in every WG (identical fp32 ops -> identical).
// One global flag-barrier per iteration for the g_h partial reduction.
__global__ __launch_bounds__(NT) void k_ep(const float* __restrict__ W2,
                                           const float* __restrict__ b_h,
                                           const float* __restrict__ b_out,
                                           const float* __restrict__ h0,
                                           const float* __restrict__ o0,
                                           const int* __restrict__ n_iter_p,
                                           const float* __restrict__ eps_p,
                                           const float* __restrict__ xW1,
                                           float* __restrict__ partials,  // [2][NWG][HID]
                                           int* __restrict__ cnt,         // [896] zeroed
                                           float* __restrict__ out) {
  __shared__ float w2t[SLICE * LD];   // col-major: w2t[j*LD + i] = W2[i][jbase+j]  (132 KB)
  __shared__ float rh_s[HID];
  __shared__ float ro_s[SLICE];
  __shared__ float red[8 * HID];      // per-jg partial rows for g_h

  const int t  = threadIdx.x;
  const int wg = blockIdx.x;
  const int jbase = wg * SLICE;
  const int n_iter = *n_iter_p;
  const float eps  = *eps_p;

  // ---- stage W2 slice into LDS (coalesced global reads; one-time LDS write conflicts OK)
#pragma unroll 1
  for (int k = 0; k < (SLICE * HID) / NT; ++k) {
    const int idx = t + k * NT;
    const int j = idx & (SLICE - 1);
    const int i = idx >> 8;
    w2t[j * LD + i] = W2[(size_t)i * OUT + jbase + j];
  }

  // ---- per-thread state
  float hh = 0.f, mh = 0.f, vh = 0.f, bhx = 0.f;     // h-state (threads 0..127, replicated per WG)
  if (t < HID) {
    hh  = h0[t];
    bhx = b_h[t] + xW1[t];
    rh_s[t] = fminf(fmaxf(hh, 0.f), 1.f);
  }
  float oo = o0[jbase + t];                           // o-state (one element per thread)
  float mo = 0.f, vo = 0.f;
  const float bo = b_out[jbase + t];
  ro_s[t] = fminf(fmaxf(oo, 0.f), 1.f);
  __syncthreads();

  float bp1 = 1.f, bp2 = 1.f;

  for (int it = 0; it < n_iter; ++it) {
    bp1 *= 0.9f; bp2 *= 0.999f;
    const float c1 = 1.f / (1.f - bp1);
    const float c2 = 1.f / (1.f - bp2);
    float* pbuf = partials + (size_t)(it & 1) * NWG * HID;

    // ---- Pass B: g_h partials over own columns (uses OLD r_o) ----
    {
      const int i4 = (t & 31) << 2;   // rows i4..i4+3
      const int jg = t >> 5;          // 8 groups of 32 cols
      float a0 = 0.f, a1 = 0.f, a2 = 0.f, a3 = 0.f;
#pragma unroll 8
      for (int jj = 0; jj < 32; ++jj) {
        const int j = (jg << 5) + jj;
        const float4 w = *(const float4*)&w2t[j * LD + i4];
        const float ro = ro_s[j];
        a0 = fmaf(w.x, ro, a0); a1 = fmaf(w.y, ro, a1);
        a2 = fmaf(w.z, ro, a2); a3 = fmaf(w.w, ro, a3);
      }
      *(float4*)&red[jg * HID + i4] = make_float4(a0, a1, a2, a3);
    }
    __syncthreads();
    if (t < HID) {
      float p = 0.f;
#pragma unroll
      for (int jg = 0; jg < 8; ++jg) p += red[jg * HID + t];
      __hip_atomic_store(&pbuf[wg * HID + t], p, __ATOMIC_RELAXED, __HIP_MEMORY_SCOPE_AGENT);
    }
    __syncthreads();                  // drains all waves' vmcnt -> stores are out
    if (t == 0) {
      __threadfence();
      __hip_atomic_fetch_add(&cnt[it], 1, __ATOMIC_RELEASE, __HIP_MEMORY_SCOPE_AGENT);
    }

    // ---- Pass A (overlaps barrier): g_o + Adam(o) (uses OLD r_h) ----
    {
      float s = 0.f;
      const float* col = &w2t[t * LD];
#pragma unroll 8
      for (int i4 = 0; i4 < HID; i4 += 4) {
        const float4 w  = *(const float4*)&col[i4];
        const float4 rh = *(const float4*)&rh_s[i4];
        s = fmaf(w.x, rh.x, s); s = fmaf(w.y, rh.y, s);
        s = fmaf(w.z, rh.z, s); s = fmaf(w.w, rh.w, s);
      }
      const float ro_old = fminf(fmaxf(oo, 0.f), 1.f);
      const float g = (oo >= 0.f && oo <= 1.f) ? (ro_old - bo - s) : 0.f;
      mo = 0.9f * mo + 0.1f * g;
      vo = 0.999f * vo + 0.001f * g * g;
      oo -= eps * (mo * c1) / (sqrtf(vo * c2) + 1e-8f);
      ro_s[t] = fminf(fmaxf(oo, 0.f), 1.f);   // safe: next reader is Pass B after barriers
    }

    // ---- wait for all WGs' partials ----
    if (t == 0) {
      while (__hip_atomic_load(&cnt[it], __ATOMIC_ACQUIRE, __HIP_MEMORY_SCOPE_AGENT) < NWG) {
        __builtin_amdgcn_s_sleep(2);
      }
    }
    __syncthreads();

    // ---- g_h reduce + Adam(h), replicated in every WG ----
    if (t < HID) {
      float gsum = 0.f;
#pragma unroll
      for (int w = 0; w < NWG; ++w)
        gsum += __hip_atomic_load(&pbuf[w * HID + t], __ATOMIC_RELAXED, __HIP_MEMORY_SCOPE_AGENT);
      const float rh_old = fminf(fmaxf(hh, 0.f), 1.f);
      const float g = (hh >= 0.f && hh <= 1.f) ? (rh_old - bhx - gsum) : 0.f;
      mh = 0.9f * mh + 0.1f * g;
      vh = 0.999f * vh + 0.001f * g * g;
      hh -= eps * (mh * c1) / (sqrtf(vh * c2) + 1e-8f);
      rh_s[t] = fminf(fmaxf(hh, 0.f), 1.f);
    }
    __syncthreads();
  }

  out[jbase + t] = oo;
}

// ---------------- launcher ----------------------------------------------------------
extern "C" void kernel_launch(void* const* d_in, const int* in_sizes, int n_in,
                              void* d_out, int out_size, void* d_ws, size_t ws_size,
                              hipStream_t stream) {
  const float* x     = (const float*)d_in[0];
  const float* W1    = (const float*)d_in[1];
  const float* W2    = (const float*)d_in[2];
  // d_in[3] = b_in (unused by the reference)
  const float* b_h   = (const float*)d_in[4];
  const float* b_out = (const float*)d_in[5];
  const float* h0    = (const float*)d_in[6];
  const float* o0    = (const float*)d_in[7];
  const int*   nit   = (const int*)d_in[8];
  const float* eps   = (const float*)d_in[9];

  float* xW1      = (float*)d_ws;                      // 128 f
  int*   cnt      = (int*)((char*)d_ws + 512);         // 896 ints (per-iteration flags)
  float* partials = (float*)((char*)d_ws + 4096);      // 2 x 16 x 128 f
  float* out      = (float*)d_out;

  // zero xW1 accumulator + iteration counters (ws is poisoned before every launch)
  hipMemsetAsync(d_ws, 0, 4096, stream);

  k_xw1<<<dim3(256), dim3(NT), 0, stream>>>(x, W1, xW1);
  k_ep<<<dim3(NWG), dim3(NT), 0, stream>>>(W2, b_h, b_out, h0, o0, nit, eps,
                                           xW1, partials, cnt, out);
}